// Round 4
// baseline (720.368 us; speedup 1.0000x reference)
//
#include <hip/hip_runtime.h>
#include <stdint.h>

#define S_LEN 4096
#define DMODEL 768
#define NHEAD 12
#define DHEAD 64
#define NBLK 64
#define FF 3072
#define NLAYER 2
#define NMID (NHEAD * (NBLK - 2))   // 744 mid workgroups
#define NEDGE_WG (NHEAD * 2 * 8)    // 192 edge partial workgroups

typedef __attribute__((ext_vector_type(8))) short short8;
typedef __attribute__((ext_vector_type(4))) float floatx4;
typedef unsigned short ushort_t;

// ---------- helpers ----------
__device__ __forceinline__ unsigned short f2bf(float f) {
    union { float f; unsigned u; } v; v.f = f;
    unsigned r = v.u + 0x7FFFu + ((v.u >> 16) & 1u);  // RNE
    return (unsigned short)(r >> 16);
}

__device__ __forceinline__ float fast_gelu(float v) {
    float u = 0.7978845608f * (v + 0.044715f * v * v * v);
    float e = __expf(2.0f * u);
    float th = 1.0f - 2.0f / (e + 1.0f);
    return 0.5f * v * (1.0f + th);
}

__device__ __forceinline__ void load_lds16(const void* g, void* l) {
    __builtin_amdgcn_global_load_lds((const __attribute__((address_space(1))) void*)g,
                                     (__attribute__((address_space(3))) void*)l, 16, 0, 0);
}

// ---------- embedding + LN ----------
__global__ void embed_ln_kernel(const int* __restrict__ ids, const float* __restrict__ wemb,
                                const float* __restrict__ pemb, const float* __restrict__ w,
                                const float* __restrict__ b, float* __restrict__ hf,
                                ushort_t* __restrict__ hb) {
    int s = blockIdx.x, t = threadIdx.x;
    const float* we = wemb + (size_t)ids[s] * DMODEL;
    const float* pe = pemb + (size_t)s * DMODEL;
    float x0 = we[t] + pe[t];
    float x1 = we[t + 256] + pe[t + 256];
    float x2 = we[t + 512] + pe[t + 512];
    float sum = x0 + x1 + x2;
    float sum2 = x0 * x0 + x1 * x1 + x2 * x2;
    __shared__ float sred[8];
    for (int o = 32; o >= 1; o >>= 1) { sum += __shfl_down(sum, o); sum2 += __shfl_down(sum2, o); }
    if ((t & 63) == 0) { sred[t >> 6] = sum; sred[4 + (t >> 6)] = sum2; }
    __syncthreads();
    float ts = sred[0] + sred[1] + sred[2] + sred[3];
    float ts2 = sred[4] + sred[5] + sred[6] + sred[7];
    float mu = ts * (1.0f / DMODEL);
    float rs = rsqrtf(ts2 * (1.0f / DMODEL) - mu * mu + 1e-12f);
    size_t base = (size_t)s * DMODEL;
    float y0 = (x0 - mu) * rs * w[t] + b[t];
    float y1 = (x1 - mu) * rs * w[t + 256] + b[t + 256];
    float y2 = (x2 - mu) * rs * w[t + 512] + b[t + 512];
    hf[base + t] = y0; hf[base + t + 256] = y1; hf[base + t + 512] = y2;
    hb[base + t] = f2bf(y0); hb[base + t + 256] = f2bf(y1); hb[base + t + 512] = f2bf(y2);
}

// ---------- LN ----------
__global__ void ln_kernel(const float* __restrict__ in, const float* __restrict__ w,
                          const float* __restrict__ b, float* __restrict__ hf,
                          ushort_t* __restrict__ hb) {
    int s = blockIdx.x, t = threadIdx.x;
    const float* row = in + (size_t)s * DMODEL;
    float x0 = row[t], x1 = row[t + 256], x2 = row[t + 512];
    float sum = x0 + x1 + x2;
    float sum2 = x0 * x0 + x1 * x1 + x2 * x2;
    __shared__ float sred[8];
    for (int o = 32; o >= 1; o >>= 1) { sum += __shfl_down(sum, o); sum2 += __shfl_down(sum2, o); }
    if ((t & 63) == 0) { sred[t >> 6] = sum; sred[4 + (t >> 6)] = sum2; }
    __syncthreads();
    float ts = sred[0] + sred[1] + sred[2] + sred[3];
    float ts2 = sred[4] + sred[5] + sred[6] + sred[7];
    float mu = ts * (1.0f / DMODEL);
    float rs = rsqrtf(ts2 * (1.0f / DMODEL) - mu * mu + 1e-12f);
    size_t base = (size_t)s * DMODEL;
    float y0 = (x0 - mu) * rs * w[t] + b[t];
    float y1 = (x1 - mu) * rs * w[t + 256] + b[t + 256];
    float y2 = (x2 - mu) * rs * w[t + 512] + b[t + 512];
    hf[base + t] = y0; hf[base + t + 256] = y1; hf[base + t + 512] = y2;
    hb[base + t] = f2bf(y0); hb[base + t + 256] = f2bf(y1); hb[base + t + 512] = f2bf(y2);
}

// ---------- init: out[m][n] = bias[n] + resid[m][n]  (float4) ----------
__global__ void init_addbias(const float* __restrict__ bias, const float* __restrict__ resid,
                             float* __restrict__ out, int Nq) {  // Nq = N/4
    int idx = blockIdx.x * 256 + threadIdx.x;
    int col4 = idx % Nq;
    float4 b4 = *(const float4*)&bias[col4 * 4];
    float4 r4 = ((const float4*)resid)[idx];
    float4 o4 = {r4.x + b4.x, r4.y + b4.y, r4.z + b4.z, r4.w + b4.w};
    ((float4*)out)[idx] = o4;
}

// ---------- batched fp32 (K x N) -> bf16 transposed (N x K), all weights, both layers ----------
__global__ void transpose_all(const float* __restrict__ Wq, const float* __restrict__ Wk,
                              const float* __restrict__ Wv, const float* __restrict__ Wo,
                              const float* __restrict__ W1, const float* __restrict__ W2,
                              ushort_t* __restrict__ WqkvT, ushort_t* __restrict__ WoT,
                              ushort_t* __restrict__ W1T, ushort_t* __restrict__ W2T) {
    __shared__ float tile[32][33];
    int b = blockIdx.x;
    int layer = b / 6912;
    b %= 6912;
    size_t lwo = (size_t)layer * DMODEL * DMODEL;   // per-layer fp32 weight offset (D*D mats)
    size_t lwf = (size_t)layer * DMODEL * FF;
    const float* src; ushort_t* dst; int K, N, bx;
    if (b < 2304) {                    // Wq/Wk/Wv/Wo: 4 x (24x24 blocks)
        int m = b / 576, r = b % 576;
        src = ((m == 0) ? Wq : (m == 1) ? Wk : (m == 2) ? Wv : Wo) + lwo;
        dst = (m < 3) ? (WqkvT + (size_t)layer * 3 * DMODEL * DMODEL + (size_t)m * DMODEL * DMODEL)
                      : (WoT + (size_t)layer * DMODEL * DMODEL);
        K = DMODEL; N = DMODEL; bx = r;
    } else if (b < 4608) {             // W1: 768 x 3072
        src = W1 + lwf; dst = W1T + (size_t)layer * DMODEL * FF; K = DMODEL; N = FF; bx = b - 2304;
    } else {                           // W2: 3072 x 768
        src = W2 + lwf; dst = W2T + (size_t)layer * DMODEL * FF; K = FF; N = DMODEL; bx = b - 4608;
    }
    int gx = N / 32;
    int n0 = (bx % gx) * 32, k0 = (bx / gx) * 32;
    int tx = threadIdx.x, ty = threadIdx.y;  // 32 x 8
    for (int i = 0; i < 32; i += 8)
        tile[ty + i][tx] = src[(size_t)(k0 + ty + i) * N + n0 + tx];
    __syncthreads();
    for (int i = 0; i < 32; i += 8)
        dst[(size_t)(n0 + ty + i) * K + k0 + tx] = f2bf(tile[tx][ty + i]);
}

// ---------- bf16 MFMA GEMM, BK=64, fused epilogues ----------
// MODE 0: QKV scatter; MODE 2: bf16 gelu(acc+bias); MODE 3: atomicAdd fp32 (split-K)
template <int MODE>
__global__ __launch_bounds__(256, 2) void gemm_bf16(
    const ushort_t* __restrict__ A, const ushort_t* __restrict__ BT,
    int M, int N, int K,
    const float* __restrict__ bias, const float* __restrict__ resid,
    float* __restrict__ outf, ushort_t* __restrict__ outb,
    ushort_t* __restrict__ qout, ushort_t* __restrict__ kout, ushort_t* __restrict__ vout,
    const float* __restrict__ bq, const float* __restrict__ bk, const float* __restrict__ bv) {
    __shared__ __align__(16) ushort_t Asm[128 * 64];
    __shared__ __align__(16) ushort_t Bsm[128 * 64];
    int tid = threadIdx.x;
    int lane = tid & 63, wave = tid >> 6;
    int quad = lane >> 4, l16 = lane & 15;
    int wm = wave >> 1, wn = wave & 1;
    long arow0 = (long)blockIdx.y * 128;
    long bcol0 = (long)blockIdx.x * 128;
    int kper = K / gridDim.z;
    int kbeg = blockIdx.z * kper, kend = kbeg + kper;
    int r8 = lane >> 3;
    int gchunk = (lane & 7) ^ (r8 & 7);
    const ushort_t* agp0 = A + (arow0 + r8) * (long)K + gchunk * 8;
    const ushort_t* bgp0 = BT + (bcol0 + r8) * (long)K + gchunk * 8;
    floatx4 acc[4][4];
#pragma unroll
    for (int i = 0; i < 4; i++)
#pragma unroll
        for (int j = 0; j < 4; j++) acc[i][j] = (floatx4){0.f, 0.f, 0.f, 0.f};

    for (int k0 = kbeg; k0 < kend; k0 += 64) {
        __syncthreads();
#pragma unroll
        for (int t2 = 0; t2 < 4; t2++) {
            int seg = wave * 4 + t2;  // 8 rows per segment
            load_lds16(agp0 + (long)seg * 8 * K + k0, Asm + seg * 512);
            load_lds16(bgp0 + (long)seg * 8 * K + k0, Bsm + seg * 512);
        }
        __syncthreads();
#pragma unroll
        for (int ks = 0; ks < 2; ks++) {
            short8 af[4], bfv[4];
#pragma unroll
            for (int i = 0; i < 4; i++)
                af[i] = *(const short8*)&Asm[(wm * 64 + i * 16 + l16) * 64 +
                                             (((ks * 4 + quad) ^ (l16 & 7)) * 8)];
#pragma unroll
            for (int j = 0; j < 4; j++)
                bfv[j] = *(const short8*)&Bsm[(wn * 64 + j * 16 + l16) * 64 +
                                              (((ks * 4 + quad) ^ (l16 & 7)) * 8)];
#pragma unroll
            for (int i = 0; i < 4; i++)
#pragma unroll
                for (int j = 0; j < 4; j++)
                    acc[i][j] = __builtin_amdgcn_mfma_f32_16x16x32_bf16(af[i], bfv[j], acc[i][j], 0, 0, 0);
        }
    }

#pragma unroll
    for (int i = 0; i < 4; i++) {
        long row = arow0 + wm * 64 + i * 16 + quad * 4;
#pragma unroll
        for (int j = 0; j < 4; j++) {
            long col = bcol0 + wn * 64 + j * 16 + l16;
#pragma unroll
            for (int r = 0; r < 4; r++) {
                float v = acc[i][j][r];
                long rw = row + r;
                if (MODE == 0) {
                    int n = (int)col;
                    if (n < DMODEL) {
                        v = (v + bq[n]) * 0.125f;
                        int hh = n >> 6, dh = n & 63;
                        qout[((long)hh * S_LEN + rw) * DHEAD + dh] = f2bf(v);
                    } else if (n < 2 * DMODEL) {
                        int n2 = n - DMODEL; v += bk[n2];
                        int hh = n2 >> 6, dh = n2 & 63;
                        kout[((long)hh * S_LEN + rw) * DHEAD + dh] = f2bf(v);
                    } else {
                        int n2 = n - 2 * DMODEL; v += bv[n2];
                        int hh = n2 >> 6, dh = n2 & 63;
                        vout[((long)hh * S_LEN + rw) * DHEAD + dh] = f2bf(v);
                    }
                } else if (MODE == 2) {
                    v += bias[col];
                    outb[rw * (long)N + col] = f2bf(fast_gelu(v));
                } else {  // MODE 3: split-K accumulate
                    atomicAdd(&outf[rw * (long)N + col], v);
                }
            }
        }
    }
}

// ---------- BigBird attention, load-balanced (mid direct, edges split-K) ----------
__global__ __launch_bounds__(256, 2) void attn_kernel(
    const ushort_t* __restrict__ qb, const ushort_t* __restrict__ kb,
    const ushort_t* __restrict__ vb, const int* __restrict__ randl,
    ushort_t* __restrict__ out, float* __restrict__ opart, float* __restrict__ mlpart) {
    __shared__ __align__(16) ushort_t Ks[64 * 72];
    __shared__ __align__(16) ushort_t Vs[64 * 72];
    __shared__ __align__(16) ushort_t Ps[4][16 * 72];
    __shared__ int kls[8];
    int tid = threadIdx.x, lane = tid & 63, wave = tid >> 6, quad = lane >> 4, l16 = lane & 15;
    int g = blockIdx.x;
    int h, qblk, chunk = 0, eidx = 0;
    bool mid;
    if (g < NMID) {
        mid = true;
        h = g / (NBLK - 2);
        qblk = 1 + g % (NBLK - 2);
    } else {
        mid = false;
        int t = g - NMID;
        int side = t / (NHEAD * 8);
        int t2 = t % (NHEAD * 8);
        h = t2 >> 3;
        chunk = t2 & 7;
        qblk = side ? (NBLK - 1) : 0;
        eidx = side * NHEAD + h;
    }
    if (mid && tid < 8) {
        int v;
        if (tid == 0) v = 0;
        else if (tid == 1) v = NBLK - 1;
        else if (tid == 2) v = qblk - 1;
        else if (tid == 3) v = qblk;
        else if (tid == 4) v = qblk + 1;
        else v = randl[(h * NBLK + qblk) * 3 + (tid - 5)];
        kls[tid] = v;
    }
    const ushort_t* qh = qb + (size_t)h * S_LEN * DHEAD;
    const ushort_t* kh = kb + (size_t)h * S_LEN * DHEAD;
    const ushort_t* vh = vb + (size_t)h * S_LEN * DHEAD;
    size_t qoff = ((size_t)(qblk * 64 + wave * 16 + l16)) * DHEAD;
    short8 qf0 = *(const short8*)&qh[qoff + quad * 8];
    short8 qf1 = *(const short8*)&qh[qoff + 32 + quad * 8];
    floatx4 oacc[4];
#pragma unroll
    for (int j = 0; j < 4; j++) oacc[j] = (floatx4){0.f, 0.f, 0.f, 0.f};
    float mrun[4] = {-1e30f, -1e30f, -1e30f, -1e30f};
    float lrun[4] = {0.f, 0.f, 0.f, 0.f};

    for (int it = 0; it < 8; ++it) {
        __syncthreads();
        int kbi = mid ? kls[it] : (chunk * 8 + it);
        {
            const ushort_t* src = kh + (size_t)kbi * 64 * DHEAD;
#pragma unroll
            for (int c = 0; c < 2; c++) {
                int chk = tid + c * 256;
                int krow = chk >> 3, kc = chk & 7;
                *(uint4*)&Ks[krow * 72 + kc * 8] = *(const uint4*)&src[chk * 8];
            }
            const ushort_t* vsrc = vh + (size_t)kbi * 64 * DHEAD;
#pragma unroll
            for (int c = 0; c < 2; c++) {
                int dh0 = wave * 16 + c * 8;
                uint4 d4 = *(const uint4*)&vsrc[lane * DHEAD + dh0];
                const ushort_t* e = (const ushort_t*)&d4;
#pragma unroll
                for (int j = 0; j < 8; j++) Vs[(dh0 + j) * 72 + lane] = e[j];
            }
        }
        __syncthreads();
        floatx4 sacc[4];
#pragma unroll
        for (int jt = 0; jt < 4; jt++) {
            short8 kf0 = *(const short8*)&Ks[(jt * 16 + l16) * 72 + quad * 8];
            short8 kf1 = *(const short8*)&Ks[(jt * 16 + l16) * 72 + 32 + quad * 8];
            floatx4 z = (floatx4){0.f, 0.f, 0.f, 0.f};
            z = __builtin_amdgcn_mfma_f32_16x16x32_bf16(qf0, kf0, z, 0, 0, 0);
            z = __builtin_amdgcn_mfma_f32_16x16x32_bf16(qf1, kf1, z, 0, 0, 0);
            sacc[jt] = z;
        }
#pragma unroll
        for (int r = 0; r < 4; r++) {
            float mx = fmaxf(fmaxf(sacc[0][r], sacc[1][r]), fmaxf(sacc[2][r], sacc[3][r]));
#pragma unroll
            for (int o = 1; o < 16; o <<= 1) mx = fmaxf(mx, __shfl_xor(mx, o));
            float mnew = fmaxf(mrun[r], mx);
            float al = __expf(mrun[r] - mnew);
            float pv[4], ps = 0.f;
#pragma unroll
            for (int jt = 0; jt < 4; jt++) { pv[jt] = __expf(sacc[jt][r] - mnew); ps += pv[jt]; }
#pragma unroll
            for (int o = 1; o < 16; o <<= 1) ps += __shfl_xor(ps, o);
            lrun[r] = lrun[r] * al + ps;
            mrun[r] = mnew;
#pragma unroll
            for (int jt = 0; jt < 4; jt++) {
                oacc[jt][r] *= al;
                Ps[wave][(quad * 4 + r) * 72 + jt * 16 + l16] = f2bf(pv[jt]);
            }
        }
        short8 pa0 = *(const short8*)&Ps[wave][l16 * 72 + quad * 8];
        short8 pa1 = *(const short8*)&Ps[wave][l16 * 72 + 32 + quad * 8];
#pragma unroll
        for (int jt = 0; jt < 4; jt++) {
            short8 vf0 = *(const short8*)&Vs[(jt * 16 + l16) * 72 + quad * 8];
            short8 vf1 = *(const short8*)&Vs[(jt * 16 + l16) * 72 + 32 + quad * 8];
            oacc[jt] = __builtin_amdgcn_mfma_f32_16x16x32_bf16(pa0, vf0, oacc[jt], 0, 0, 0);
            oacc[jt] = __builtin_amdgcn_mfma_f32_16x16x32_bf16(pa1, vf1, oacc[jt], 0, 0, 0);
        }
    }
    if (mid) {
#pragma unroll
        for (int jt = 0; jt < 4; jt++)
#pragma unroll
            for (int r = 0; r < 4; r++) {
                int row = qblk * 64 + wave * 16 + quad * 4 + r;
                int col = h * DHEAD + jt * 16 + l16;
                out[(size_t)row * DMODEL + col] = f2bf(oacc[jt][r] / lrun[r]);
            }
    } else {
        float* op = opart + ((size_t)(eidx * 8 + chunk)) * 64 * 64;
        float* ml = mlpart + ((size_t)(eidx * 8 + chunk)) * 64 * 2;
#pragma unroll
        for (int jt = 0; jt < 4; jt++)
#pragma unroll
            for (int r = 0; r < 4; r++) {
                int row = wave * 16 + quad * 4 + r;
                op[(size_t)row * 64 + jt * 16 + l16] = oacc[jt][r];
            }
        if (l16 == 0) {
#pragma unroll
            for (int r = 0; r < 4; r++) {
                int row = wave * 16 + quad * 4 + r;
                ml[row * 2 + 0] = mrun[r];
                ml[row * 2 + 1] = lrun[r];
            }
        }
    }
}

// ---------- merge edge split-K partials ----------
__global__ void attn_combine(const float* __restrict__ opart, const float* __restrict__ mlpart,
                             ushort_t* __restrict__ out) {
    int e = blockIdx.x;                  // 0..23
    int side = e / NHEAD, h = e % NHEAD;
    int qblk = side ? (NBLK - 1) : 0;
    __shared__ float mls[8][64][2];
    int tid = threadIdx.x;
    for (int i = tid; i < 8 * 64 * 2; i += 256)
        ((float*)mls)[i] = mlpart[(size_t)e * 8 * 64 * 2 + i];
    __syncthreads();
    int col = tid & 63, r0 = (tid >> 6) * 16;
    const float* ope = opart + (size_t)e * 8 * 64 * 64;
    for (int row = r0; row < r0 + 16; ++row) {
        float M = -1e30f;
#pragma unroll
        for (int p = 0; p < 8; p++) M = fmaxf(M, mls[p][row][0]);
        float L = 0.f, O = 0.f;
#pragma unroll
        for (int p = 0; p < 8; p++) {
            float al = __expf(mls[p][row][0] - M);
            L += mls[p][row][1] * al;
            O += ope[((size_t)p * 64 + row) * 64 + col] * al;
        }
        out[(size_t)(qblk * 64 + row) * DMODEL + h * DHEAD + col] = f2bf(O / L);
    }
}

// ---------- classifier ----------
__global__ void classifier_kernel(const float* __restrict__ hf, const float* __restrict__ Wc,
                                  const float* __restrict__ bc, float* __restrict__ out) {
    int t = threadIdx.x;
    int c = t & 7, seg = t >> 3;
    const float* hr = hf + (size_t)(S_LEN - 1) * DMODEL;
    float p = 0.f;
    for (int i = 0; i < 24; i++) { int d = seg * 24 + i; p += hr[d] * Wc[d * 8 + c]; }
    __shared__ float red[256];
    red[t] = p;
    __syncthreads();
    for (int o = 128; o >= 8; o >>= 1) { if (t < o) red[t] += red[t + o]; __syncthreads(); }
    if (t < 8) out[t] = red[t] + bc[t];
}

// ---------- launch ----------
extern "C" void kernel_launch(void* const* d_in, const int* in_sizes, int n_in,
                              void* d_out, int out_size, void* d_ws, size_t ws_size,
                              hipStream_t stream) {
    (void)in_sizes; (void)n_in; (void)out_size; (void)ws_size;
    const int* input_ids = (const int*)d_in[0];
    const int* rand_attn = (const int*)d_in[1];
    const float* word_emb = (const float*)d_in[2];
    const float* pos_emb = (const float*)d_in[3];
    const float* emb_ln_w = (const float*)d_in[4];
    const float* emb_ln_b = (const float*)d_in[5];
    const float* Wq = (const float*)d_in[6];
    const float* bq = (const float*)d_in[7];
    const float* Wk = (const float*)d_in[8];
    const float* bk = (const float*)d_in[9];
    const float* Wv = (const float*)d_in[10];
    const float* bv = (const float*)d_in[11];
    const float* Wo = (const float*)d_in[12];
    const float* bo = (const float*)d_in[13];
    const float* ln1_w = (const float*)d_in[14];
    const float* ln1_b = (const float*)d_in[15];
    const float* W1 = (const float*)d_in[16];
    const float* b1 = (const float*)d_in[17];
    const float* W2 = (const float*)d_in[18];
    const float* b2 = (const float*)d_in[19];
    const float* ln2_w = (const float*)d_in[20];
    const float* ln2_b = (const float*)d_in[21];
    const float* Wc = (const float*)d_in[22];
    const float* bc = (const float*)d_in[23];
    float* outp = (float*)d_out;

    char* ws = (char*)d_ws;
    size_t off = 0;
    auto alloc = [&](size_t bytes) -> void* {
        void* p = ws + off;
        off += (bytes + 255) & ~(size_t)255;
        return p;
    };
    float* hf = (float*)alloc((size_t)S_LEN * DMODEL * 4);
    ushort_t* hb = (ushort_t*)alloc((size_t)S_LEN * DMODEL * 2);
    float* res = (float*)alloc((size_t)S_LEN * DMODEL * 4);
    ushort_t* WqkvT = (ushort_t*)alloc((size_t)NLAYER * 3 * DMODEL * DMODEL * 2);
    ushort_t* WoT = (ushort_t*)alloc((size_t)NLAYER * DMODEL * DMODEL * 2);
    ushort_t* W1T = (ushort_t*)alloc((size_t)NLAYER * FF * DMODEL * 2);
    ushort_t* W2T = (ushort_t*)alloc((size_t)NLAYER * DMODEL * FF * 2);
    ushort_t* qbuf = (ushort_t*)alloc((size_t)NHEAD * S_LEN * DHEAD * 2);
    ushort_t* kbuf = (ushort_t*)alloc((size_t)NHEAD * S_LEN * DHEAD * 2);
    ushort_t* vbuf = (ushort_t*)alloc((size_t)NHEAD * S_LEN * DHEAD * 2);
    ushort_t* attnb = (ushort_t*)alloc((size_t)S_LEN * DMODEL * 2);
    ushort_t* gbuf = (ushort_t*)alloc((size_t)S_LEN * FF * 2);
    float* opart = (float*)alloc((size_t)24 * 8 * 64 * 64 * 4);
    float* mlpart = (float*)alloc((size_t)24 * 8 * 64 * 2 * 4);

    dim3 blk256(256);
    dim3 tb(32, 8);

    embed_ln_kernel<<<S_LEN, blk256, 0, stream>>>(input_ids, word_emb, pos_emb,
                                                  emb_ln_w, emb_ln_b, hf, hb);
    transpose_all<<<NLAYER * 6912, tb, 0, stream>>>(Wq, Wk, Wv, Wo, W1, W2,
                                                    WqkvT, WoT, W1T, W2T);

    for (int l = 0; l < NLAYER; ++l) {
        const ushort_t* WqkvT_l = WqkvT + (size_t)l * 3 * DMODEL * DMODEL;
        const ushort_t* WoT_l = WoT + (size_t)l * DMODEL * DMODEL;
        const ushort_t* W1T_l = W1T + (size_t)l * FF * DMODEL;
        const ushort_t* W2T_l = W2T + (size_t)l * DMODEL * FF;
        const float* bq_l = bq + (size_t)l * DMODEL;
        const float* bk_l = bk + (size_t)l * DMODEL;
        const float* bv_l = bv + (size_t)l * DMODEL;
        const float* bo_l = bo + (size_t)l * DMODEL;
        const float* b1_l = b1 + (size_t)l * FF;
        const float* b2_l = b2 + (size_t)l * DMODEL;
        const float* ln1w_l = ln1_w + (size_t)l * DMODEL;
        const float* ln1b_l = ln1_b + (size_t)l * DMODEL;
        const float* ln2w_l = ln2_w + (size_t)l * DMODEL;
        const float* ln2b_l = ln2_b + (size_t)l * DMODEL;
        const int* rand_l = rand_attn + (size_t)l * NHEAD * NBLK * 3;

        gemm_bf16<0><<<dim3(3 * DMODEL / 128, S_LEN / 128, 1), blk256, 0, stream>>>(
            hb, WqkvT_l, S_LEN, 3 * DMODEL, DMODEL,
            nullptr, nullptr, nullptr, nullptr, qbuf, kbuf, vbuf, bq_l, bk_l, bv_l);

        attn_kernel<<<NMID + NEDGE_WG, blk256, 0, stream>>>(qbuf, kbuf, vbuf, rand_l,
                                                            attnb, opart, mlpart);
        attn_combine<<<24, blk256, 0, stream>>>(opart, mlpart, attnb);

        // Wo projection: res = bo + hf, then split-K 2 atomic GEMM
        init_addbias<<<S_LEN * DMODEL / 4 / 256, blk256, 0, stream>>>(bo_l, hf, res, DMODEL / 4);
        gemm_bf16<3><<<dim3(DMODEL / 128, S_LEN / 128, 2), blk256, 0, stream>>>(
            attnb, WoT_l, S_LEN, DMODEL, DMODEL,
            nullptr, nullptr, res, nullptr, nullptr, nullptr, nullptr, nullptr, nullptr, nullptr);

        ln_kernel<<<S_LEN, blk256, 0, stream>>>(res, ln1w_l, ln1b_l, hf, hb);

        gemm_bf16<2><<<dim3(FF / 128, S_LEN / 128, 1), blk256, 0, stream>>>(
            hb, W1T_l, S_LEN, FF, DMODEL,
            b1_l, nullptr, nullptr, gbuf, nullptr, nullptr, nullptr, nullptr, nullptr, nullptr);

        // FFN2: res = b2 + hf, then split-K 4 atomic GEMM
        init_addbias<<<S_LEN * DMODEL / 4 / 256, blk256, 0, stream>>>(b2_l, hf, res, DMODEL / 4);
        gemm_bf16<3><<<dim3(DMODEL / 128, S_LEN / 128, 4), blk256, 0, stream>>>(
            gbuf, W2T_l, S_LEN, DMODEL, FF,
            nullptr, nullptr, res, nullptr, nullptr, nullptr, nullptr, nullptr, nullptr, nullptr);

        ln_kernel<<<S_LEN, blk256, 0, stream>>>(res, ln2w_l, ln2b_l, hf, hb);
    }

    classifier_kernel<<<1, blk256, 0, stream>>>(hf, Wc, bc, outp);
}

// Round 5
// 617.840 us; speedup vs baseline: 1.1659x; 1.1659x over previous
//
#include <hip/hip_runtime.h>
#include <stdint.h>

#define S_LEN 4096
#define DMODEL 768
#define NHEAD 12
#define DHEAD 64
#define NBLK 64
#define FF 3072
#define NLAYER 2
#define NMID (NHEAD * (NBLK - 2))   // 744 mid workgroups
#define NEDGE_WG (NHEAD * 2 * 8)    // 192 edge partial workgroups

typedef __attribute__((ext_vector_type(8))) short short8;
typedef __attribute__((ext_vector_type(4))) float floatx4;
typedef unsigned short ushort_t;

// ---------- helpers ----------
__device__ __forceinline__ unsigned short f2bf(float f) {
    union { float f; unsigned u; } v; v.f = f;
    unsigned r = v.u + 0x7FFFu + ((v.u >> 16) & 1u);  // RNE
    return (unsigned short)(r >> 16);
}

__device__ __forceinline__ float fast_gelu(float v) {
    float u = 0.7978845608f * (v + 0.044715f * v * v * v);
    float e = __expf(2.0f * u);
    float th = 1.0f - 2.0f / (e + 1.0f);
    return 0.5f * v * (1.0f + th);
}

__device__ __forceinline__ void load_lds16(const void* g, void* l) {
    __builtin_amdgcn_global_load_lds((const __attribute__((address_space(1))) void*)g,
                                     (__attribute__((address_space(3))) void*)l, 16, 0, 0);
}

// ---------- embedding + LN ----------
__global__ void embed_ln_kernel(const int* __restrict__ ids, const float* __restrict__ wemb,
                                const float* __restrict__ pemb, const float* __restrict__ w,
                                const float* __restrict__ b, float* __restrict__ hf,
                                ushort_t* __restrict__ hb) {
    int s = blockIdx.x, t = threadIdx.x;
    const float* we = wemb + (size_t)ids[s] * DMODEL;
    const float* pe = pemb + (size_t)s * DMODEL;
    float x0 = we[t] + pe[t];
    float x1 = we[t + 256] + pe[t + 256];
    float x2 = we[t + 512] + pe[t + 512];
    float sum = x0 + x1 + x2;
    float sum2 = x0 * x0 + x1 * x1 + x2 * x2;
    __shared__ float sred[8];
    for (int o = 32; o >= 1; o >>= 1) { sum += __shfl_down(sum, o); sum2 += __shfl_down(sum2, o); }
    if ((t & 63) == 0) { sred[t >> 6] = sum; sred[4 + (t >> 6)] = sum2; }
    __syncthreads();
    float ts = sred[0] + sred[1] + sred[2] + sred[3];
    float ts2 = sred[4] + sred[5] + sred[6] + sred[7];
    float mu = ts * (1.0f / DMODEL);
    float rs = rsqrtf(ts2 * (1.0f / DMODEL) - mu * mu + 1e-12f);
    size_t base = (size_t)s * DMODEL;
    float y0 = (x0 - mu) * rs * w[t] + b[t];
    float y1 = (x1 - mu) * rs * w[t + 256] + b[t + 256];
    float y2 = (x2 - mu) * rs * w[t + 512] + b[t + 512];
    hf[base + t] = y0; hf[base + t + 256] = y1; hf[base + t + 512] = y2;
    hb[base + t] = f2bf(y0); hb[base + t + 256] = f2bf(y1); hb[base + t + 512] = f2bf(y2);
}

// ---------- LN fused with split-K reduce: x = resid + bias + sum_p parts[p] ----------
// NOTE: resid and hf may alias (in-place) — no __restrict__ on them.
template <int NP>
__global__ void ln_fused(const float* __restrict__ parts, const float* resid,
                         const float* __restrict__ bias, const float* __restrict__ w,
                         const float* __restrict__ b, float* hf, ushort_t* __restrict__ hb) {
    int s = blockIdx.x, t = threadIdx.x;
    size_t base = (size_t)s * DMODEL;
    const size_t PS = (size_t)S_LEN * DMODEL;
    float x0 = resid[base + t] + bias[t];
    float x1 = resid[base + t + 256] + bias[t + 256];
    float x2 = resid[base + t + 512] + bias[t + 512];
#pragma unroll
    for (int p = 0; p < NP; p++) {
        const float* pp = parts + p * PS + base;
        x0 += pp[t]; x1 += pp[t + 256]; x2 += pp[t + 512];
    }
    float sum = x0 + x1 + x2;
    float sum2 = x0 * x0 + x1 * x1 + x2 * x2;
    __shared__ float sred[8];
    for (int o = 32; o >= 1; o >>= 1) { sum += __shfl_down(sum, o); sum2 += __shfl_down(sum2, o); }
    if ((t & 63) == 0) { sred[t >> 6] = sum; sred[4 + (t >> 6)] = sum2; }
    __syncthreads();
    float ts = sred[0] + sred[1] + sred[2] + sred[3];
    float ts2 = sred[4] + sred[5] + sred[6] + sred[7];
    float mu = ts * (1.0f / DMODEL);
    float rs = rsqrtf(ts2 * (1.0f / DMODEL) - mu * mu + 1e-12f);
    float y0 = (x0 - mu) * rs * w[t] + b[t];
    float y1 = (x1 - mu) * rs * w[t + 256] + b[t + 256];
    float y2 = (x2 - mu) * rs * w[t + 512] + b[t + 512];
    hf[base + t] = y0; hf[base + t + 256] = y1; hf[base + t + 512] = y2;
    hb[base + t] = f2bf(y0); hb[base + t + 256] = f2bf(y1); hb[base + t + 512] = f2bf(y2);
}

// ---------- batched fp32 (K x N) -> bf16 transposed (N x K), all weights, both layers ----------
__global__ void transpose_all(const float* __restrict__ Wq, const float* __restrict__ Wk,
                              const float* __restrict__ Wv, const float* __restrict__ Wo,
                              const float* __restrict__ W1, const float* __restrict__ W2,
                              ushort_t* __restrict__ WqkvT, ushort_t* __restrict__ WoT,
                              ushort_t* __restrict__ W1T, ushort_t* __restrict__ W2T) {
    __shared__ float tile[32][33];
    int b = blockIdx.x;
    int layer = b / 6912;
    b %= 6912;
    size_t lwo = (size_t)layer * DMODEL * DMODEL;
    size_t lwf = (size_t)layer * DMODEL * FF;
    const float* src; ushort_t* dst; int K, N, bx;
    if (b < 2304) {
        int m = b / 576, r = b % 576;
        src = ((m == 0) ? Wq : (m == 1) ? Wk : (m == 2) ? Wv : Wo) + lwo;
        dst = (m < 3) ? (WqkvT + (size_t)layer * 3 * DMODEL * DMODEL + (size_t)m * DMODEL * DMODEL)
                      : (WoT + (size_t)layer * DMODEL * DMODEL);
        K = DMODEL; N = DMODEL; bx = r;
    } else if (b < 4608) {
        src = W1 + lwf; dst = W1T + (size_t)layer * DMODEL * FF; K = DMODEL; N = FF; bx = b - 2304;
    } else {
        src = W2 + lwf; dst = W2T + (size_t)layer * DMODEL * FF; K = FF; N = DMODEL; bx = b - 4608;
    }
    int gx = N / 32;
    int n0 = (bx % gx) * 32, k0 = (bx / gx) * 32;
    int tx = threadIdx.x, ty = threadIdx.y;  // 32 x 8
    for (int i = 0; i < 32; i += 8)
        tile[ty + i][tx] = src[(size_t)(k0 + ty + i) * N + n0 + tx];
    __syncthreads();
    for (int i = 0; i < 32; i += 8)
        dst[(size_t)(n0 + ty + i) * K + k0 + tx] = f2bf(tile[tx][ty + i]);
}

// ---------- bf16 MFMA GEMM, BK=64, fused epilogues ----------
// MODE 0: QKV scatter; MODE 2: bf16 gelu(acc+bias); MODE 3: split-K fp32 partial store
template <int MODE>
__global__ __launch_bounds__(256, 2) void gemm_bf16(
    const ushort_t* __restrict__ A, const ushort_t* __restrict__ BT,
    int M, int N, int K,
    const float* __restrict__ bias, float* __restrict__ outf, ushort_t* __restrict__ outb,
    ushort_t* __restrict__ qout, ushort_t* __restrict__ kout, ushort_t* __restrict__ vout,
    const float* __restrict__ bq, const float* __restrict__ bk, const float* __restrict__ bv) {
    __shared__ __align__(16) ushort_t Asm[128 * 64];
    __shared__ __align__(16) ushort_t Bsm[128 * 64];
    int tid = threadIdx.x;
    int lane = tid & 63, wave = tid >> 6;
    int quad = lane >> 4, l16 = lane & 15;
    int wm = wave >> 1, wn = wave & 1;
    long arow0 = (long)blockIdx.y * 128;
    long bcol0 = (long)blockIdx.x * 128;
    int kper = K / gridDim.z;
    int kbeg = blockIdx.z * kper, kend = kbeg + kper;
    int r8 = lane >> 3;
    int gchunk = (lane & 7) ^ (r8 & 7);
    const ushort_t* agp0 = A + (arow0 + r8) * (long)K + gchunk * 8;
    const ushort_t* bgp0 = BT + (bcol0 + r8) * (long)K + gchunk * 8;
    floatx4 acc[4][4];
#pragma unroll
    for (int i = 0; i < 4; i++)
#pragma unroll
        for (int j = 0; j < 4; j++) acc[i][j] = (floatx4){0.f, 0.f, 0.f, 0.f};

    for (int k0 = kbeg; k0 < kend; k0 += 64) {
        __syncthreads();
#pragma unroll
        for (int t2 = 0; t2 < 4; t2++) {
            int seg = wave * 4 + t2;  // 8 rows per segment
            load_lds16(agp0 + (long)seg * 8 * K + k0, Asm + seg * 512);
            load_lds16(bgp0 + (long)seg * 8 * K + k0, Bsm + seg * 512);
        }
        __syncthreads();
#pragma unroll
        for (int ks = 0; ks < 2; ks++) {
            short8 af[4], bfv[4];
#pragma unroll
            for (int i = 0; i < 4; i++)
                af[i] = *(const short8*)&Asm[(wm * 64 + i * 16 + l16) * 64 +
                                             (((ks * 4 + quad) ^ (l16 & 7)) * 8)];
#pragma unroll
            for (int j = 0; j < 4; j++)
                bfv[j] = *(const short8*)&Bsm[(wn * 64 + j * 16 + l16) * 64 +
                                              (((ks * 4 + quad) ^ (l16 & 7)) * 8)];
#pragma unroll
            for (int i = 0; i < 4; i++)
#pragma unroll
                for (int j = 0; j < 4; j++)
                    acc[i][j] = __builtin_amdgcn_mfma_f32_16x16x32_bf16(af[i], bfv[j], acc[i][j], 0, 0, 0);
        }
    }

    long MN = (long)M * N;
#pragma unroll
    for (int i = 0; i < 4; i++) {
        long row = arow0 + wm * 64 + i * 16 + quad * 4;
#pragma unroll
        for (int j = 0; j < 4; j++) {
            long col = bcol0 + wn * 64 + j * 16 + l16;
#pragma unroll
            for (int r = 0; r < 4; r++) {
                float v = acc[i][j][r];
                long rw = row + r;
                if (MODE == 0) {
                    int n = (int)col;
                    if (n < DMODEL) {
                        v = (v + bq[n]) * 0.125f;
                        int hh = n >> 6, dh = n & 63;
                        qout[((long)hh * S_LEN + rw) * DHEAD + dh] = f2bf(v);
                    } else if (n < 2 * DMODEL) {
                        int n2 = n - DMODEL; v += bk[n2];
                        int hh = n2 >> 6, dh = n2 & 63;
                        kout[((long)hh * S_LEN + rw) * DHEAD + dh] = f2bf(v);
                    } else {
                        int n2 = n - 2 * DMODEL; v += bv[n2];
                        int hh = n2 >> 6, dh = n2 & 63;
                        vout[((long)hh * S_LEN + rw) * DHEAD + dh] = f2bf(v);
                    }
                } else if (MODE == 2) {
                    v += bias[col];
                    outb[rw * (long)N + col] = f2bf(fast_gelu(v));
                } else {  // MODE 3: deterministic split-K partial (plain stores)
                    outf[(long)blockIdx.z * MN + rw * (long)N + col] = v;
                }
            }
        }
    }
}

// ---------- BigBird attention, load-balanced (mid direct, edges split-K) ----------
__global__ __launch_bounds__(256, 2) void attn_kernel(
    const ushort_t* __restrict__ qb, const ushort_t* __restrict__ kb,
    const ushort_t* __restrict__ vb, const int* __restrict__ randl,
    ushort_t* __restrict__ out, float* __restrict__ opart, float* __restrict__ mlpart) {
    __shared__ __align__(16) ushort_t Ks[64 * 72];
    __shared__ __align__(16) ushort_t Vs[64 * 72];
    __shared__ __align__(16) ushort_t Ps[4][16 * 72];
    __shared__ int kls[8];
    int tid = threadIdx.x, lane = tid & 63, wave = tid >> 6, quad = lane >> 4, l16 = lane & 15;
    int g = blockIdx.x;
    int h, qblk, chunk = 0, eidx = 0;
    bool mid;
    if (g < NMID) {
        mid = true;
        h = g / (NBLK - 2);
        qblk = 1 + g % (NBLK - 2);
    } else {
        mid = false;
        int t = g - NMID;
        int side = t / (NHEAD * 8);
        int t2 = t % (NHEAD * 8);
        h = t2 >> 3;
        chunk = t2 & 7;
        qblk = side ? (NBLK - 1) : 0;
        eidx = side * NHEAD + h;
    }
    if (mid && tid < 8) {
        int v;
        if (tid == 0) v = 0;
        else if (tid == 1) v = NBLK - 1;
        else if (tid == 2) v = qblk - 1;
        else if (tid == 3) v = qblk;
        else if (tid == 4) v = qblk + 1;
        else v = randl[(h * NBLK + qblk) * 3 + (tid - 5)];
        kls[tid] = v;
    }
    const ushort_t* qh = qb + (size_t)h * S_LEN * DHEAD;
    const ushort_t* kh = kb + (size_t)h * S_LEN * DHEAD;
    const ushort_t* vh = vb + (size_t)h * S_LEN * DHEAD;
    size_t qoff = ((size_t)(qblk * 64 + wave * 16 + l16)) * DHEAD;
    short8 qf0 = *(const short8*)&qh[qoff + quad * 8];
    short8 qf1 = *(const short8*)&qh[qoff + 32 + quad * 8];
    floatx4 oacc[4];
#pragma unroll
    for (int j = 0; j < 4; j++) oacc[j] = (floatx4){0.f, 0.f, 0.f, 0.f};
    float mrun[4] = {-1e30f, -1e30f, -1e30f, -1e30f};
    float lrun[4] = {0.f, 0.f, 0.f, 0.f};

    for (int it = 0; it < 8; ++it) {
        __syncthreads();
        int kbi = mid ? kls[it] : (chunk * 8 + it);
        {
            const ushort_t* src = kh + (size_t)kbi * 64 * DHEAD;
#pragma unroll
            for (int c = 0; c < 2; c++) {
                int chk = tid + c * 256;
                int krow = chk >> 3, kc = chk & 7;
                *(uint4*)&Ks[krow * 72 + kc * 8] = *(const uint4*)&src[chk * 8];
            }
            const ushort_t* vsrc = vh + (size_t)kbi * 64 * DHEAD;
#pragma unroll
            for (int c = 0; c < 2; c++) {
                int dh0 = wave * 16 + c * 8;
                uint4 d4 = *(const uint4*)&vsrc[lane * DHEAD + dh0];
                const ushort_t* e = (const ushort_t*)&d4;
#pragma unroll
                for (int j = 0; j < 8; j++) Vs[(dh0 + j) * 72 + lane] = e[j];
            }
        }
        __syncthreads();
        floatx4 sacc[4];
#pragma unroll
        for (int jt = 0; jt < 4; jt++) {
            short8 kf0 = *(const short8*)&Ks[(jt * 16 + l16) * 72 + quad * 8];
            short8 kf1 = *(const short8*)&Ks[(jt * 16 + l16) * 72 + 32 + quad * 8];
            floatx4 z = (floatx4){0.f, 0.f, 0.f, 0.f};
            z = __builtin_amdgcn_mfma_f32_16x16x32_bf16(qf0, kf0, z, 0, 0, 0);
            z = __builtin_amdgcn_mfma_f32_16x16x32_bf16(qf1, kf1, z, 0, 0, 0);
            sacc[jt] = z;
        }
#pragma unroll
        for (int r = 0; r < 4; r++) {
            float mx = fmaxf(fmaxf(sacc[0][r], sacc[1][r]), fmaxf(sacc[2][r], sacc[3][r]));
#pragma unroll
            for (int o = 1; o < 16; o <<= 1) mx = fmaxf(mx, __shfl_xor(mx, o));
            float mnew = fmaxf(mrun[r], mx);
            float al = __expf(mrun[r] - mnew);
            float pv[4], ps = 0.f;
#pragma unroll
            for (int jt = 0; jt < 4; jt++) { pv[jt] = __expf(sacc[jt][r] - mnew); ps += pv[jt]; }
#pragma unroll
            for (int o = 1; o < 16; o <<= 1) ps += __shfl_xor(ps, o);
            lrun[r] = lrun[r] * al + ps;
            mrun[r] = mnew;
#pragma unroll
            for (int jt = 0; jt < 4; jt++) {
                oacc[jt][r] *= al;
                Ps[wave][(quad * 4 + r) * 72 + jt * 16 + l16] = f2bf(pv[jt]);
            }
        }
        short8 pa0 = *(const short8*)&Ps[wave][l16 * 72 + quad * 8];
        short8 pa1 = *(const short8*)&Ps[wave][l16 * 72 + 32 + quad * 8];
#pragma unroll
        for (int jt = 0; jt < 4; jt++) {
            short8 vf0 = *(const short8*)&Vs[(jt * 16 + l16) * 72 + quad * 8];
            short8 vf1 = *(const short8*)&Vs[(jt * 16 + l16) * 72 + 32 + quad * 8];
            oacc[jt] = __builtin_amdgcn_mfma_f32_16x16x32_bf16(pa0, vf0, oacc[jt], 0, 0, 0);
            oacc[jt] = __builtin_amdgcn_mfma_f32_16x16x32_bf16(pa1, vf1, oacc[jt], 0, 0, 0);
        }
    }
    if (mid) {
#pragma unroll
        for (int jt = 0; jt < 4; jt++)
#pragma unroll
            for (int r = 0; r < 4; r++) {
                int row = qblk * 64 + wave * 16 + quad * 4 + r;
                int col = h * DHEAD + jt * 16 + l16;
                out[(size_t)row * DMODEL + col] = f2bf(oacc[jt][r] / lrun[r]);
            }
    } else {
        float* op = opart + ((size_t)(eidx * 8 + chunk)) * 64 * 64;
        float* ml = mlpart + ((size_t)(eidx * 8 + chunk)) * 64 * 2;
#pragma unroll
        for (int jt = 0; jt < 4; jt++)
#pragma unroll
            for (int r = 0; r < 4; r++) {
                int row = wave * 16 + quad * 4 + r;
                op[(size_t)row * 64 + jt * 16 + l16] = oacc[jt][r];
            }
        if (l16 == 0) {
#pragma unroll
            for (int r = 0; r < 4; r++) {
                int row = wave * 16 + quad * 4 + r;
                ml[row * 2 + 0] = mrun[r];
                ml[row * 2 + 1] = lrun[r];
            }
        }
    }
}

// ---------- merge edge split-K partials ----------
__global__ void attn_combine(const float* __restrict__ opart, const float* __restrict__ mlpart,
                             ushort_t* __restrict__ out) {
    int e = blockIdx.x;                  // 0..23
    int side = e / NHEAD, h = e % NHEAD;
    int qblk = side ? (NBLK - 1) : 0;
    __shared__ float mls[8][64][2];
    int tid = threadIdx.x;
    for (int i = tid; i < 8 * 64 * 2; i += 256)
        ((float*)mls)[i] = mlpart[(size_t)e * 8 * 64 * 2 + i];
    __syncthreads();
    int col = tid & 63, r0 = (tid >> 6) * 16;
    const float* ope = opart + (size_t)e * 8 * 64 * 64;
    for (int row = r0; row < r0 + 16; ++row) {
        float M = -1e30f;
#pragma unroll
        for (int p = 0; p < 8; p++) M = fmaxf(M, mls[p][row][0]);
        float L = 0.f, O = 0.f;
#pragma unroll
        for (int p = 0; p < 8; p++) {
            float al = __expf(mls[p][row][0] - M);
            L += mls[p][row][1] * al;
            O += ope[((size_t)p * 64 + row) * 64 + col] * al;
        }
        out[(size_t)(qblk * 64 + row) * DMODEL + h * DHEAD + col] = f2bf(O / L);
    }
}

// ---------- classifier ----------
__global__ void classifier_kernel(const float* __restrict__ hf, const float* __restrict__ Wc,
                                  const float* __restrict__ bc, float* __restrict__ out) {
    int t = threadIdx.x;
    int c = t & 7, seg = t >> 3;
    const float* hr = hf + (size_t)(S_LEN - 1) * DMODEL;
    float p = 0.f;
    for (int i = 0; i < 24; i++) { int d = seg * 24 + i; p += hr[d] * Wc[d * 8 + c]; }
    __shared__ float red[256];
    red[t] = p;
    __syncthreads();
    for (int o = 128; o >= 8; o >>= 1) { if (t < o) red[t] += red[t + o]; __syncthreads(); }
    if (t < 8) out[t] = red[t] + bc[t];
}

// ---------- launch ----------
extern "C" void kernel_launch(void* const* d_in, const int* in_sizes, int n_in,
                              void* d_out, int out_size, void* d_ws, size_t ws_size,
                              hipStream_t stream) {
    (void)in_sizes; (void)n_in; (void)out_size; (void)ws_size;
    const int* input_ids = (const int*)d_in[0];
    const int* rand_attn = (const int*)d_in[1];
    const float* word_emb = (const float*)d_in[2];
    const float* pos_emb = (const float*)d_in[3];
    const float* emb_ln_w = (const float*)d_in[4];
    const float* emb_ln_b = (const float*)d_in[5];
    const float* Wq = (const float*)d_in[6];
    const float* bq = (const float*)d_in[7];
    const float* Wk = (const float*)d_in[8];
    const float* bk = (const float*)d_in[9];
    const float* Wv = (const float*)d_in[10];
    const float* bv = (const float*)d_in[11];
    const float* Wo = (const float*)d_in[12];
    const float* bo = (const float*)d_in[13];
    const float* ln1_w = (const float*)d_in[14];
    const float* ln1_b = (const float*)d_in[15];
    const float* W1 = (const float*)d_in[16];
    const float* b1 = (const float*)d_in[17];
    const float* W2 = (const float*)d_in[18];
    const float* b2 = (const float*)d_in[19];
    const float* ln2_w = (const float*)d_in[20];
    const float* ln2_b = (const float*)d_in[21];
    const float* Wc = (const float*)d_in[22];
    const float* bc = (const float*)d_in[23];
    float* outp = (float*)d_out;

    char* ws = (char*)d_ws;
    size_t off = 0;
    auto alloc = [&](size_t bytes) -> void* {
        void* p = ws + off;
        off += (bytes + 255) & ~(size_t)255;
        return p;
    };
    float* hf = (float*)alloc((size_t)S_LEN * DMODEL * 4);
    ushort_t* hb = (ushort_t*)alloc((size_t)S_LEN * DMODEL * 2);
    float* fpart = (float*)alloc((size_t)4 * S_LEN * DMODEL * 4);   // split-K partials
    ushort_t* WqkvT = (ushort_t*)alloc((size_t)NLAYER * 3 * DMODEL * DMODEL * 2);
    ushort_t* WoT = (ushort_t*)alloc((size_t)NLAYER * DMODEL * DMODEL * 2);
    ushort_t* W1T = (ushort_t*)alloc((size_t)NLAYER * FF * DMODEL * 2);
    ushort_t* W2T = (ushort_t*)alloc((size_t)NLAYER * DMODEL * FF * 2);
    ushort_t* qbuf = (ushort_t*)alloc((size_t)NHEAD * S_LEN * DHEAD * 2);
    ushort_t* kbuf = (ushort_t*)alloc((size_t)NHEAD * S_LEN * DHEAD * 2);
    ushort_t* vbuf = (ushort_t*)alloc((size_t)NHEAD * S_LEN * DHEAD * 2);
    ushort_t* attnb = (ushort_t*)alloc((size_t)S_LEN * DMODEL * 2);
    ushort_t* gbuf = (ushort_t*)alloc((size_t)S_LEN * FF * 2);
    float* opart = (float*)alloc((size_t)24 * 8 * 64 * 64 * 4);
    float* mlpart = (float*)alloc((size_t)24 * 8 * 64 * 2 * 4);

    dim3 blk256(256);
    dim3 tb(32, 8);

    embed_ln_kernel<<<S_LEN, blk256, 0, stream>>>(input_ids, word_emb, pos_emb,
                                                  emb_ln_w, emb_ln_b, hf, hb);
    transpose_all<<<NLAYER * 6912, tb, 0, stream>>>(Wq, Wk, Wv, Wo, W1, W2,
                                                    WqkvT, WoT, W1T, W2T);

    for (int l = 0; l < NLAYER; ++l) {
        const ushort_t* WqkvT_l = WqkvT + (size_t)l * 3 * DMODEL * DMODEL;
        const ushort_t* WoT_l = WoT + (size_t)l * DMODEL * DMODEL;
        const ushort_t* W1T_l = W1T + (size_t)l * FF * DMODEL;
        const ushort_t* W2T_l = W2T + (size_t)l * DMODEL * FF;
        const float* bq_l = bq + (size_t)l * DMODEL;
        const float* bk_l = bk + (size_t)l * DMODEL;
        const float* bv_l = bv + (size_t)l * DMODEL;
        const float* bo_l = bo + (size_t)l * DMODEL;
        const float* b1_l = b1 + (size_t)l * FF;
        const float* b2_l = b2 + (size_t)l * DMODEL;
        const float* ln1w_l = ln1_w + (size_t)l * DMODEL;
        const float* ln1b_l = ln1_b + (size_t)l * DMODEL;
        const float* ln2w_l = ln2_w + (size_t)l * DMODEL;
        const float* ln2b_l = ln2_b + (size_t)l * DMODEL;
        const int* rand_l = rand_attn + (size_t)l * NHEAD * NBLK * 3;

        gemm_bf16<0><<<dim3(3 * DMODEL / 128, S_LEN / 128, 1), blk256, 0, stream>>>(
            hb, WqkvT_l, S_LEN, 3 * DMODEL, DMODEL,
            nullptr, nullptr, nullptr, qbuf, kbuf, vbuf, bq_l, bk_l, bv_l);

        attn_kernel<<<NMID + NEDGE_WG, blk256, 0, stream>>>(qbuf, kbuf, vbuf, rand_l,
                                                            attnb, opart, mlpart);
        attn_combine<<<24, blk256, 0, stream>>>(opart, mlpart, attnb);

        // Wo projection: split-K 2 partials, then LN fuses resid + bo + partials
        gemm_bf16<3><<<dim3(DMODEL / 128, S_LEN / 128, 2), blk256, 0, stream>>>(
            attnb, WoT_l, S_LEN, DMODEL, DMODEL,
            nullptr, fpart, nullptr, nullptr, nullptr, nullptr, nullptr, nullptr, nullptr);
        ln_fused<2><<<S_LEN, blk256, 0, stream>>>(fpart, hf, bo_l, ln1w_l, ln1b_l, hf, hb);

        gemm_bf16<2><<<dim3(FF / 128, S_LEN / 128, 1), blk256, 0, stream>>>(
            hb, W1T_l, S_LEN, FF, DMODEL,
            b1_l, nullptr, gbuf, nullptr, nullptr, nullptr, nullptr, nullptr, nullptr);

        // FFN2: split-K 4 partials, then LN fuses resid + b2 + partials
        gemm_bf16<3><<<dim3(DMODEL / 128, S_LEN / 128, 4), blk256, 0, stream>>>(
            gbuf, W2T_l, S_LEN, DMODEL, FF,
            nullptr, fpart, nullptr, nullptr, nullptr, nullptr, nullptr, nullptr, nullptr);
        ln_fused<4><<<S_LEN, blk256, 0, stream>>>(fpart, hf, b2_l, ln2w_l, ln2b_l, hf, hb);
    }

    classifier_kernel<<<1, blk256, 0, stream>>>(hf, Wc, bc, outp);
}